// Round 2
// 294.860 us; speedup vs baseline: 1.0390x; 1.0390x over previous
//
#include <hip/hip_runtime.h>
#include <hip/hip_bf16.h>

#define BATCH   4
#define SEQ     2048
#define DMODEL  1024
#define NHEADS  16
#define DHEAD   64
#define MROWS   (BATCH*SEQ)        // 8192
#define QKV_N   (3*DMODEL)         // 3072
#define NEG_BIG (-1.0e30f)
#define WS_NEED ((size_t)MROWS * 2*DMODEL * sizeof(__hip_bfloat16))  // 33,554,432
#define SCALE_Q 0.18033688011112042f   // 0.125 * log2(e); folded into Q at projection

using bf16 = __hip_bfloat16;
typedef __attribute__((ext_vector_type(8))) short short8;
typedef __attribute__((ext_vector_type(4))) float floatx4;

// Static device buffers (module BSS; no hipMalloc)
__device__ __align__(16) unsigned short g_wqT[QKV_N * DMODEL];   // W_qkv^T bf16
__device__ __align__(16) unsigned short g_woT[DMODEL * DMODEL];  // W_out^T bf16
__device__ __align__(16) unsigned short g_xb [MROWS * DMODEL];   // x bf16

__device__ __forceinline__ unsigned short f2bf_rne(float f) {
    union { bf16 b; unsigned short u; } t;
    t.b = __float2bfloat16(f);
    return t.u;
}

// async global->LDS, 16B per lane; LDS dest = wave-uniform base + lane*16
__device__ __forceinline__ void gload_lds16(const void* g, void* l) {
    __builtin_amdgcn_global_load_lds(
        (const __attribute__((address_space(1))) unsigned*)g,
        (__attribute__((address_space(3))) unsigned*)l, 16, 0, 0);
}

// ---------------------------------------------------------------------------
// x fp32 -> bf16
// ---------------------------------------------------------------------------
__global__ __launch_bounds__(256) void cast_x(const float* __restrict__ x) {
    const size_t i = ((size_t)blockIdx.x*256 + threadIdx.x)*8;
    const float4 a = *(const float4*)(x + i);
    const float4 b = *(const float4*)(x + i + 4);
    union { uint4 u4; unsigned short us[8]; } o;
    o.us[0]=f2bf_rne(a.x); o.us[1]=f2bf_rne(a.y); o.us[2]=f2bf_rne(a.z); o.us[3]=f2bf_rne(a.w);
    o.us[4]=f2bf_rne(b.x); o.us[5]=f2bf_rne(b.y); o.us[6]=f2bf_rne(b.z); o.us[7]=f2bf_rne(b.w);
    *(uint4*)(g_xb + i) = o.u4;
}

// ---------------------------------------------------------------------------
// Weight transpose + cast: W fp32 [1024][N] -> dst bf16 [N][1024]
// ---------------------------------------------------------------------------
__global__ __launch_bounds__(256) void transcast_w(
    const float* __restrict__ W, int N, int which)
{
    unsigned short* dst = which ? g_woT : g_wqT;
    __shared__ unsigned short T[64][72];
    const int n0 = blockIdx.x * 64, k0 = blockIdx.y * 64;
    const int tid = threadIdx.x;
    const int r = tid >> 2, c0 = (tid & 3) * 16;

#pragma unroll
    for (int it = 0; it < 4; ++it) {
        const float4 v = *(const float4*)(W + (size_t)(k0 + r)*N + n0 + c0 + it*4);
        T[r][c0 + it*4 + 0] = f2bf_rne(v.x);
        T[r][c0 + it*4 + 1] = f2bf_rne(v.y);
        T[r][c0 + it*4 + 2] = f2bf_rne(v.z);
        T[r][c0 + it*4 + 3] = f2bf_rne(v.w);
    }
    __syncthreads();
    const int nr = tid >> 2, kc0 = (tid & 3) * 16;
#pragma unroll
    for (int it = 0; it < 2; ++it) {
        union { uint4 u4; unsigned short us[8]; } o;
#pragma unroll
        for (int j = 0; j < 8; j++) o.us[j] = T[kc0 + it*8 + j][nr];
        *(uint4*)(dst + (size_t)(n0 + nr)*DMODEL + k0 + kc0 + it*8) = o.u4;
    }
}

// ---------------------------------------------------------------------------
// 256x256 BK=64 phase-pipelined MFMA GEMM (m201-style 8-phase schedule).
// 8 waves (512 thr). LDS 128 KiB: A,B each 2 bufs x (256x64) bf16, stored as
// 1KiB subtiles [rb=row/16][kh=k/32]; within a subtile the 16B chunk c of
// row r lives at slot c ^ ((r>>1)&3)  -> frag ds_read_b128 is 2-way (free).
// Per K-tile: 4 phases, phase q = block-quadrant (q>>1, q&1) over K=64:
//   12 ds_read_b128 + 2 global_load_lds(16B) prefetch + 16 MFMA per wave.
// Counted vmcnt (never 0 in steady state):
//   stage order per tile t (into buf^1, for tile t+1): q0:Ah0 q1:Bh0 q2:Ah1 q3:Bh1
//   q0-end vmcnt(2)  guarantees prev q2(Ah1),q3(Bh1) done  (needed q1,q2)
//   q3-end vmcnt(4)  guarantees cur q0(Ah0),q1(Bh0) done   (needed next q0)
// QKV_MODE=1: A=g_xb, B=g_wqT, epilogue splits Q|K|VT (Q pre-scaled, V
// transposed). QKV_MODE=0: A=runtime bf16, B=g_woT, fp32 C + bias.
// ---------------------------------------------------------------------------
template<int QKV_MODE>
__global__ __launch_bounds__(512, 2) void gemm256(
    const void* __restrict__ Av, const float* __restrict__ bias,
    void* __restrict__ C0, void* __restrict__ C1, void* __restrict__ C2)
{
    const unsigned short* A  = QKV_MODE ? g_xb  : (const unsigned short*)Av;
    const unsigned short* BT = QKV_MODE ? g_wqT : g_woT;

    __shared__ __align__(16) char smem[131072];   // A: [0,64K)  B: [64K,128K)
    char* const sA = smem;
    char* const sB = smem + 65536;

    const int tid  = threadIdx.x;
    const int w    = tid >> 6, lane = tid & 63;
    const int m16  = lane & 15, quad = lane >> 4;
    const int rw   = w >> 1, cw = w & 1;          // wave pos in 128x128 quadrant (4x2)
    const int bm   = blockIdx.y, bn = blockIdx.x;

    // staging lane decomposition: slot chunk (r,c) holds data chunk c^((r>>1)&3)
    const int rL = lane >> 2;
    const int cD = (lane & 3) ^ ((lane >> 3) & 3);
    const unsigned short* gA = A  + (size_t)(bm*256 + rL)*DMODEL + cD*8;
    const unsigned short* gB = BT + (size_t)(bn*256 + rL)*DMODEL + cD*8;

    // frag-read lane offset (swizzled)
    const int laneRd = m16*64 + (quad ^ ((m16 >> 1) & 3))*16;

    floatx4 acc[4][2][4];
#pragma unroll
    for (int q = 0; q < 4; ++q)
#pragma unroll
        for (int i = 0; i < 2; ++i)
#pragma unroll
            for (int j = 0; j < 4; ++j) {
                acc[q][i][j][0]=0.f; acc[q][i][j][1]=0.f;
                acc[q][i][j][2]=0.f; acc[q][i][j][3]=0.f;
            }

    // stage one 128x64 half-tile (16 subtiles); wave w covers subtiles w, w+8
    auto stageA = [&](int buf, int half, int k0) {
        char* l0 = sA + buf*32768 + half*16384 + w*1024;
        gload_lds16(gA + (size_t)(half*128 + (w>>1)*16)*DMODEL + k0 + (w&1)*32, l0);
        gload_lds16(gA + (size_t)(half*128 + ((w>>1)+4)*16)*DMODEL + k0 + (w&1)*32, l0 + 8192);
    };
    auto stageB = [&](int buf, int half, int k0) {
        char* l0 = sB + buf*32768 + half*16384 + w*1024;
        gload_lds16(gB + (size_t)(half*128 + (w>>1)*16)*DMODEL + k0 + (w&1)*32, l0);
        gload_lds16(gB + (size_t)(half*128 + ((w>>1)+4)*16)*DMODEL + k0 + (w&1)*32, l0 + 8192);
    };

    // ---- prologue: stage tile 0 fully into buf 0
    stageA(0, 0, 0); stageB(0, 0, 0); stageA(0, 1, 0); stageB(0, 1, 0);
    asm volatile("s_waitcnt vmcnt(0)" ::: "memory");
    __builtin_amdgcn_s_barrier();

    const int NT = DMODEL / 64;   // 16
    for (int t = 0; t < NT; ++t) {
        const int  buf = t & 1;
        const int  k1  = (t + 1) * 64;
        const bool st  = (t + 1 < NT);
        char* const Abuf = sA + buf*32768;
        char* const Bbuf = sB + buf*32768;

#pragma unroll
        for (int q = 0; q < 4; ++q) {
            const int qm = q >> 1, qn = q & 1;

            // ---- ds-read this phase's fragments (from buf)
            short8 af[2][2], bfr[4][2];
#pragma unroll
            for (int i = 0; i < 2; ++i)
#pragma unroll
                for (int kh = 0; kh < 2; ++kh)
                    af[i][kh] = *(const short8*)(Abuf + qm*16384
                                    + ((rw*2 + i)*2 + kh)*1024 + laneRd);
#pragma unroll
            for (int j = 0; j < 4; ++j)
#pragma unroll
                for (int kh = 0; kh < 2; ++kh)
                    bfr[j][kh] = *(const short8*)(Bbuf + qn*16384
                                    + ((cw*4 + j)*2 + kh)*1024 + laneRd);

            // ---- prefetch one half-tile of tile t+1 into buf^1
            if (st) {
                if      (q == 0) stageA(buf^1, 0, k1);
                else if (q == 1) stageB(buf^1, 0, k1);
                else if (q == 2) stageA(buf^1, 1, k1);
                else             stageB(buf^1, 1, k1);
            }

            __builtin_amdgcn_s_barrier();

            __builtin_amdgcn_s_setprio(1);
#pragma unroll
            for (int i = 0; i < 2; ++i)
#pragma unroll
                for (int j = 0; j < 4; ++j) {
                    acc[q][i][j] = __builtin_amdgcn_mfma_f32_16x16x32_bf16(
                        af[i][0], bfr[j][0], acc[q][i][j], 0, 0, 0);
                    acc[q][i][j] = __builtin_amdgcn_mfma_f32_16x16x32_bf16(
                        af[i][1], bfr[j][1], acc[q][i][j], 0, 0, 0);
                }
            __builtin_amdgcn_s_setprio(0);

            // ---- counted waits (per schedule proof in header comment)
            if (q == 0) {
                if (st) { asm volatile("s_waitcnt vmcnt(2)" ::: "memory"); }
                else    { asm volatile("s_waitcnt vmcnt(0)" ::: "memory"); }
            }
            if (q == 3) {
                if (st) { asm volatile("s_waitcnt vmcnt(4)" ::: "memory"); }
                else    { asm volatile("s_waitcnt vmcnt(0)" ::: "memory"); }
            }
            __builtin_amdgcn_s_barrier();
        }
    }

    // ---- epilogue
    float bv[2][4];
#pragma unroll
    for (int qn = 0; qn < 2; ++qn)
#pragma unroll
        for (int j = 0; j < 4; ++j)
            bv[qn][j] = bias[bn*256 + qn*128 + cw*64 + j*16 + m16];

    if (QKV_MODE) {
        const int seg = bn >> 2;           // 0=Q(scaled), 1=K, 2=V(transposed)
        if (seg < 2) {
            bf16* Cout = (bf16*)(seg ? C1 : C0);
            const float sc = seg ? 1.0f : SCALE_Q;
#pragma unroll
            for (int q = 0; q < 4; ++q) {
                const int qm = q >> 1, qn = q & 1;
#pragma unroll
                for (int i = 0; i < 2; ++i)
#pragma unroll
                    for (int r = 0; r < 4; ++r) {
                        const int gm = bm*256 + qm*128 + rw*32 + i*16 + quad*4 + r;
#pragma unroll
                        for (int j = 0; j < 4; ++j) {
                            const int cc = (bn*256 + qn*128 + cw*64 + j*16 + m16) & 1023;
                            Cout[(size_t)gm*DMODEL + cc] =
                                __float2bfloat16((acc[q][i][j][r] + bv[qn][j]) * sc);
                        }
                    }
            }
        } else {
            bf16* VT = (bf16*)C2;
#pragma unroll
            for (int q = 0; q < 4; ++q) {
                const int qm = q >> 1, qn = q & 1;
#pragma unroll
                for (int i = 0; i < 2; ++i) {
                    const int gm0 = bm*256 + qm*128 + rw*32 + i*16 + quad*4;
                    const int bb = gm0 >> 11, t0 = gm0 & 2047;
#pragma unroll
                    for (int j = 0; j < 4; ++j) {
                        const int cv = (bn*256 + qn*128 + cw*64 + j*16 + m16) & 1023;
                        const int hh = cv >> 6, dd = cv & 63;
                        union { unsigned long long u8; unsigned short us[4]; } o;
#pragma unroll
                        for (int r = 0; r < 4; ++r)
                            o.us[r] = f2bf_rne(acc[q][i][j][r] + bv[qn][j]);
                        *(unsigned long long*)(VT
                            + ((size_t)((bb*NHEADS + hh)*DHEAD + dd))*SEQ + t0) = o.u8;
                    }
                }
            }
        }
    } else {
        float* Cout = (float*)C0;
#pragma unroll
        for (int q = 0; q < 4; ++q) {
            const int qm = q >> 1, qn = q & 1;
#pragma unroll
            for (int i = 0; i < 2; ++i)
#pragma unroll
                for (int r = 0; r < 4; ++r) {
                    const int gm = bm*256 + qm*128 + rw*32 + i*16 + quad*4 + r;
#pragma unroll
                    for (int j = 0; j < 4; ++j) {
                        const int cc = (bn*256 + qn*128 + cw*64 + j*16 + m16) & 1023;
                        Cout[(size_t)gm*DMODEL + cc] = acc[q][i][j][r] + bv[qn][j];
                    }
                }
        }
    }
}

// ---------------------------------------------------------------------------
// MFMA flash attention v3 — transposed formulation. S^T = K·Q^T and
// O^T = V^T·P^T via operand-swapped MFMAs (A/B frags share layout, so the
// swap is free). Each lane owns ONE q-column per i-group: softmax reduction
// = 15 in-reg ops + 2 shuffle rounds; m/l/alpha scalar per lane; P^T and O
// stored as packed b64 (4 consecutive keys/dims per reg quad). Q arrives
// pre-scaled by 0.125*log2(e) -> exp2-based online softmax.
// Block = paired q-tiles {p, 15-p} (uniform 34 iters); dbuf K/V tiles.
// ---------------------------------------------------------------------------
__global__ __launch_bounds__(256, 2) void attn_mfma3(
    const bf16* __restrict__ Qg, const bf16* __restrict__ Kg,
    const bf16* __restrict__ VTg, bf16* __restrict__ Og)
{
    __shared__ alignas(16) unsigned short Kt[2][64][72];   // [buf][key][d]
    __shared__ alignas(16) unsigned short Vt[2][64][72];   // [buf][d][key]
    __shared__ alignas(16) unsigned short Ps[4][32][72];   // [wave][q][key] = P^T cols

    const int x = blockIdx.x;
    const int b = x >> 7, h = (x >> 3) & 15, p = x & 7;
    const int tid = threadIdx.x;
    const int w = tid >> 6, lane = tid & 63;
    const int m16 = lane & 15, quad = lane >> 4;
    const int sr = tid >> 2, sc0 = (tid & 3) * 8;
    const size_t bh = (size_t)(b*NHEADS + h);

    for (int seg = 0; seg < 2; ++seg) {
        const int qt  = seg ? (15 - p) : p;
        const int nkt = 2*qt + 2;
        const int qrow0 = qt*128 + w*32;

        short8 qf[2][2];
#pragma unroll
        for (int i = 0; i < 2; ++i)
#pragma unroll
            for (int c = 0; c < 2; ++c)
                qf[i][c] = *(const short8*)(Qg + (size_t)(b*SEQ + qrow0 + i*16 + m16)*DMODEL
                                            + h*DHEAD + c*32 + quad*8);

        floatx4 of[2][4];
        float mrow[2], lrow[2];
#pragma unroll
        for (int i = 0; i < 2; ++i) {
            mrow[i] = NEG_BIG; lrow[i] = 0.f;
#pragma unroll
            for (int nt = 0; nt < 4; ++nt) { of[i][nt][0]=0.f; of[i][nt][1]=0.f; of[i][nt][2]=0.f; of[i][nt][3]=0.f; }
        }

        // ---- stage tile 0 into buf 0
        {
            const bf16* kp = Kg  + (size_t)(b*SEQ + sr)*DMODEL + h*DHEAD + sc0;
            const bf16* vp = VTg + (bh*DHEAD + sr)*SEQ + sc0;
            const uint4 a0 = *(const uint4*)kp, a1 = *(const uint4*)(kp + 32);
            const uint4 b0 = *(const uint4*)vp, b1 = *(const uint4*)(vp + 32);
            __syncthreads();
            *(uint4*)&Kt[0][sr][sc0]      = a0;
            *(uint4*)&Kt[0][sr][sc0 + 32] = a1;
            *(uint4*)&Vt[0][sr][sc0]      = b0;
            *(uint4*)&Vt[0][sr][sc0 + 32] = b1;
            __syncthreads();
        }

        for (int kt = 0; kt < nkt; ++kt) {
            const int buf = kt & 1;
            const int k064 = kt * 64;
            const bool pre = (kt + 1 < nkt);
            uint4 kr0, kr1, vr0, vr1;
            if (pre) {
                const bf16* kp = Kg  + (size_t)(b*SEQ + k064 + 64 + sr)*DMODEL + h*DHEAD + sc0;
                const bf16* vp = VTg + (bh*DHEAD + sr)*SEQ + k064 + 64 + sc0;
                kr0 = *(const uint4*)kp; kr1 = *(const uint4*)(kp + 32);
                vr0 = *(const uint4*)vp; vr1 = *(const uint4*)(vp + 32);
            }

            // ---- S^T = K Q^T (16 MFMA): rows=key(quad*4+r, t4), cols=q(m16)
            floatx4 sf[2][4];
#pragma unroll
            for (int t4 = 0; t4 < 4; ++t4) {
                const short8 kf0 = *(const short8*)&Kt[buf][t4*16 + m16][quad*8];
                const short8 kf1 = *(const short8*)&Kt[buf][t4*16 + m16][32 + quad*8];
#pragma unroll
                for (int i = 0; i < 2; ++i) {
                    floatx4 a; a[0]=0.f; a[1]=0.f; a[2]=0.f; a[3]=0.f;
                    a = __builtin_amdgcn_mfma_f32_16x16x32_bf16(kf0, qf[i][0], a, 0, 0, 0);
                    a = __builtin_amdgcn_mfma_f32_16x16x32_bf16(kf1, qf[i][1], a, 0, 0, 0);
                    sf[i][t4] = a;
                }
            }

            // ---- online softmax (per lane = per q-column)
            const bool need_mask = (k064 + 63 > qrow0);
#pragma unroll
            for (int i = 0; i < 2; ++i) {
                if (need_mask) {
                    const int qg = qrow0 + i*16 + m16;
#pragma unroll
                    for (int t4 = 0; t4 < 4; ++t4)
#pragma unroll
                        for (int r = 0; r < 4; ++r)
                            if (k064 + t4*16 + quad*4 + r > qg) sf[i][t4][r] = NEG_BIG;
                }
                float mx = sf[i][0][0];
#pragma unroll
                for (int t4 = 0; t4 < 4; ++t4)
#pragma unroll
                    for (int r = 0; r < 4; ++r) mx = fmaxf(mx, sf[i][t4][r]);
                mx = fmaxf(mx, __shfl_xor(mx, 16));
                mx = fmaxf(mx, __shfl_xor(mx, 32));

                const float mnew  = fmaxf(mrow[i], mx);
                const float alpha = exp2f(mrow[i] - mnew);
                mrow[i] = mnew;

                float rs = 0.f;
#pragma unroll
                for (int t4 = 0; t4 < 4; ++t4) {
#pragma unroll
                    for (int r = 0; r < 4; ++r) {
                        const float pv = exp2f(sf[i][t4][r] - mnew);
                        sf[i][t4][r] = pv;
                        rs += pv;
                    }
                }
                rs += __shfl_xor(rs, 16);
                rs += __shfl_xor(rs, 32);
                lrow[i] = lrow[i]*alpha + rs;
#pragma unroll
                for (int nt = 0; nt < 4; ++nt)
#pragma unroll
                    for (int r = 0; r < 4; ++r) of[i][nt][r] *= alpha;

                // P^T -> LDS: 4 consecutive keys per b64 store
#pragma unroll
                for (int t4 = 0; t4 < 4; ++t4) {
                    union { unsigned long long u8; unsigned short us[4]; } o;
#pragma unroll
                    for (int r = 0; r < 4; ++r) o.us[r] = f2bf_rne(sf[i][t4][r]);
                    *(unsigned long long*)&Ps[w][i*16 + m16][t4*16 + quad*4] = o.u8;
                }
            }

            // ---- O^T += V^T P^T (16 MFMA); Ps wave-local
            short8 pf[2][2];
#pragma unroll
            for (int i = 0; i < 2; ++i)
#pragma unroll
                for (int c = 0; c < 2; ++c)
                    pf[i][c] = *(const short8*)&Ps[w][i*16 + m16][c*32 + quad*8];
#pragma unroll
            for (int nt = 0; nt < 4; ++nt) {
                const short8 vf0 = *(const short8*)&Vt[buf][nt*16 + m16][quad*8];
                const short8 vf1 = *(const short8*)&Vt[buf][nt*16 + m16][32 + quad*8];
#pragma unroll
                for (int i = 0; i < 2; ++i) {
                    of[i][nt] = __builtin_amdgcn_mfma_f32_16x16x32_bf16(vf0, pf[i][0], of[i][nt], 0, 0, 0);
                    of[i][nt] = __builtin_amdgcn_mfma_f32_16x16x32_bf16(vf1, pf[i][1], of[i][nt], 0, 0, 0);
                }
            }

            if (pre) {
                *(uint4*)&Kt[buf^1][sr][sc0]      = kr0;
                *(uint4*)&Kt[buf^1][sr][sc0 + 32] = kr1;
                *(uint4*)&Vt[buf^1][sr][sc0]      = vr0;
                *(uint4*)&Vt[buf^1][sr][sc0 + 32] = vr1;
            }
            __syncthreads();
        }

        // ---- normalize + store O: lane owns row q, dims nt*16+quad*4+{0..3}
#pragma unroll
        for (int i = 0; i < 2; ++i) {
            const float rl = 1.f / fmaxf(lrow[i], 1e-20f);
            const size_t rowbase = (size_t)(b*SEQ + qrow0 + i*16 + m16)*DMODEL + h*DHEAD;
#pragma unroll
            for (int nt = 0; nt < 4; ++nt) {
                union { unsigned long long u8; unsigned short us[4]; } o;
#pragma unroll
                for (int r = 0; r < 4; ++r) o.us[r] = f2bf_rne(of[i][nt][r] * rl);
                *(unsigned long long*)(Og + rowbase + nt*16 + quad*4) = o.u8;
            }
        }
    }
}

__global__ void diag_fill(float* out, int n, float val) {
    int i = blockIdx.x*blockDim.x + threadIdx.x;
    if (i < n) out[i] = val;
}

// ---------------------------------------------------------------------------
extern "C" void kernel_launch(void* const* d_in, const int* in_sizes, int n_in,
                              void* d_out, int out_size, void* d_ws, size_t ws_size,
                              hipStream_t stream) {
    const float* x     = (const float*)d_in[0];
    const float* W_qkv = (const float*)d_in[1];
    const float* b_qkv = (const float*)d_in[2];
    const float* W_out = (const float*)d_in[3];
    const float* b_out = (const float*)d_in[4];

    if (ws_size < WS_NEED) {
        const float val = 100.f + (float)(ws_size >> 20);
        diag_fill<<<(out_size + 255)/256, 256, 0, stream>>>((float*)d_out, out_size, val);
        return;
    }

    bf16* Qb  = (bf16*)d_out;                                // d_out lo: Q (pre-scaled)
    bf16* VTb = (bf16*)d_out + (size_t)MROWS*DMODEL;         // d_out hi: VT
    bf16* Kb  = (bf16*)d_ws;                                 // ws lo: K
    bf16* Ob  = (bf16*)d_ws + (size_t)MROWS*DMODEL;          // ws hi: O

    // 0) casts
    cast_x<<<MROWS*DMODEL/2048, 256, 0, stream>>>(x);
    {
        dim3 gq(QKV_N/64, DMODEL/64);
        transcast_w<<<gq, 256, 0, stream>>>(W_qkv, QKV_N, 0);
        dim3 go(DMODEL/64, DMODEL/64);
        transcast_w<<<go, 256, 0, stream>>>(W_out, DMODEL, 1);
    }
    // 1) fused QKV projection; Q pre-scaled; V pre-transposed (8-phase 256^2)
    {
        dim3 g(QKV_N/256, MROWS/256);
        gemm256<1><<<g, 512, 0, stream>>>(nullptr, b_qkv, Qb, Kb, VTb);
    }
    // 2) flash attention v3 (transposed MFMA formulation)
    {
        attn_mfma3<<<512, 256, 0, stream>>>(Qb, Kb, VTb, Ob);
    }
    // 3) output projection: O bf16 -> fp32 d_out (Q/VT dead)
    {
        dim3 g(DMODEL/256, MROWS/256);
        gemm256<0><<<g, 512, 0, stream>>>(Ob, b_out, d_out, nullptr, nullptr);
    }
}

// Round 3
// 277.828 us; speedup vs baseline: 1.1027x; 1.0613x over previous
//
#include <hip/hip_runtime.h>
#include <hip/hip_bf16.h>

#define BATCH   4
#define SEQ     2048
#define DMODEL  1024
#define NHEADS  16
#define DHEAD   64
#define MROWS   (BATCH*SEQ)        // 8192
#define QKV_N   (3*DMODEL)         // 3072
#define NEG_BIG (-1.0e30f)
#define WS_NEED ((size_t)MROWS * 2*DMODEL * sizeof(__hip_bfloat16))  // 33,554,432
#define SCALE_Q 0.18033688011112042f   // 0.125 * log2(e); folded into Q at projection

using bf16 = __hip_bfloat16;
typedef __attribute__((ext_vector_type(8))) short short8;
typedef __attribute__((ext_vector_type(4))) float floatx4;

// Static device buffers (module BSS; no hipMalloc)
__device__ __align__(16) unsigned short g_wqT[QKV_N * DMODEL];   // W_qkv^T bf16
__device__ __align__(16) unsigned short g_woT[DMODEL * DMODEL];  // W_out^T bf16
__device__ __align__(16) unsigned short g_xb [MROWS * DMODEL];   // x bf16

__device__ __forceinline__ unsigned short f2bf_rne(float f) {
    union { bf16 b; unsigned short u; } t;
    t.b = __float2bfloat16(f);
    return t.u;
}

// async global->LDS, 16B per lane; LDS dest = wave-uniform base + lane*16
__device__ __forceinline__ void gload_lds16(const void* g, void* l) {
    __builtin_amdgcn_global_load_lds(
        (const __attribute__((address_space(1))) unsigned*)g,
        (__attribute__((address_space(3))) unsigned*)l, 16, 0, 0);
}

// ---------------------------------------------------------------------------
// x fp32 -> bf16
// ---------------------------------------------------------------------------
__global__ __launch_bounds__(256) void cast_x(const float* __restrict__ x) {
    const size_t i = ((size_t)blockIdx.x*256 + threadIdx.x)*8;
    const float4 a = *(const float4*)(x + i);
    const float4 b = *(const float4*)(x + i + 4);
    union { uint4 u4; unsigned short us[8]; } o;
    o.us[0]=f2bf_rne(a.x); o.us[1]=f2bf_rne(a.y); o.us[2]=f2bf_rne(a.z); o.us[3]=f2bf_rne(a.w);
    o.us[4]=f2bf_rne(b.x); o.us[5]=f2bf_rne(b.y); o.us[6]=f2bf_rne(b.z); o.us[7]=f2bf_rne(b.w);
    *(uint4*)(g_xb + i) = o.u4;
}

// ---------------------------------------------------------------------------
// Weight transpose + cast: W fp32 [1024][N] -> dst bf16 [N][1024]
// ---------------------------------------------------------------------------
__global__ __launch_bounds__(256) void transcast_w(
    const float* __restrict__ W, int N, int which)
{
    unsigned short* dst = which ? g_woT : g_wqT;
    __shared__ unsigned short T[64][72];
    const int n0 = blockIdx.x * 64, k0 = blockIdx.y * 64;
    const int tid = threadIdx.x;
    const int r = tid >> 2, c0 = (tid & 3) * 16;

#pragma unroll
    for (int it = 0; it < 4; ++it) {
        const float4 v = *(const float4*)(W + (size_t)(k0 + r)*N + n0 + c0 + it*4);
        T[r][c0 + it*4 + 0] = f2bf_rne(v.x);
        T[r][c0 + it*4 + 1] = f2bf_rne(v.y);
        T[r][c0 + it*4 + 2] = f2bf_rne(v.z);
        T[r][c0 + it*4 + 3] = f2bf_rne(v.w);
    }
    __syncthreads();
    const int nr = tid >> 2, kc0 = (tid & 3) * 16;
#pragma unroll
    for (int it = 0; it < 2; ++it) {
        union { uint4 u4; unsigned short us[8]; } o;
#pragma unroll
        for (int j = 0; j < 8; j++) o.us[j] = T[kc0 + it*8 + j][nr];
        *(uint4*)(dst + (size_t)(n0 + nr)*DMODEL + k0 + kc0 + it*8) = o.u4;
    }
}

// ---------------------------------------------------------------------------
// 256x128 BK=64 phase-pipelined MFMA GEMM (m201-style schedule, 2 phases).
// Fixes round-2's grid quantization: QKV grid = 768 = 3.0 clean rounds,
// outproj = 256 = 1.0 round (vs 384/128 blocks at 1 block/CU before).
// 8 waves (512 thr), wave grid 4M x 2N, per-wave output 64x64.
// LDS 96 KiB: A 2buf x 32KB (32 subtiles), B 2buf x 16KB (16 subtiles).
// Subtile = 16 rows x 32 k x 2B = 1KB; within it, 16B chunk c of row r sits
// at slot c ^ ((r>>1)&3) -> frag ds_read_b128 is conflict-free.
// Phase structure per K-tile t (buf=t&1), bf hoisted (B same for both M-halves):
//  p0: read bf[4][2]+af(qm0); stage B(t+1) [2/wave]; bar; 16 MFMA; vmcnt(2); bar
//  p1: read af(qm1);          stage A(t+1) [4/wave]; bar; 16 MFMA; vmcnt(2); bar
// Deadline audit (per-wave ledger, identical across waves):
//  issue order per tile: B'0,B'1 (p0), A'0..A'3 (p1)
//  p1-end vmcnt(2): oldest 4 (B'0,B'1,A'0,A'1) done -> t+1 p0 reads OK
//  p0-end vmcnt(2): outstanding {A'2,A'3,B''0,B''1}; oldest 2 done -> p1 OK
// XCD swizzle (bijective, nwg%8==0): blocks sharing an A-panel -> same XCD.
// ---------------------------------------------------------------------------
template<int QKV_MODE>
__global__ __launch_bounds__(512, 2) void gemm256x128(
    const void* __restrict__ Av, const float* __restrict__ bias,
    void* __restrict__ C0, void* __restrict__ C1, void* __restrict__ C2)
{
    const unsigned short* A  = QKV_MODE ? g_xb  : (const unsigned short*)Av;
    const unsigned short* BT = QKV_MODE ? g_wqT : g_woT;
    constexpr int NBN = QKV_MODE ? 24 : 8;      // N/128
    constexpr int NWG = NBN * 32;               // * (M/256)

    __shared__ __align__(16) char smem[98304];  // A: 2x32KB @0; B: 2x16KB @65536
    char* const sA = smem;
    char* const sB = smem + 65536;

    // XCD-aware bijective swizzle: consecutive hw blocks on one XCD sweep bn
    const int orig = blockIdx.x;
    const int wgid = (orig & 7) * (NWG >> 3) + (orig >> 3);
    const int bm = wgid / NBN, bn = wgid % NBN;

    const int tid  = threadIdx.x;
    const int w    = tid >> 6, lane = tid & 63;
    const int m16  = lane & 15, quad = lane >> 4;
    const int rw   = w >> 1, cw = w & 1;

    // staging lane decomposition: slot chunk (r,c) holds data chunk c^((r>>1)&3)
    const int rL = lane >> 2;
    const int cD = (lane & 3) ^ ((lane >> 3) & 3);
    const unsigned short* gA = A  + (size_t)(bm*256 + rL)*DMODEL + cD*8;
    const unsigned short* gB = BT + (size_t)(bn*128 + rL)*DMODEL + cD*8;

    // frag-read lane offset (swizzled)
    const int laneRd = m16*64 + (quad ^ ((m16 >> 1) & 3))*16;

    floatx4 acc[2][2][4];   // [qm][i][j]
#pragma unroll
    for (int q = 0; q < 2; ++q)
#pragma unroll
        for (int i = 0; i < 2; ++i)
#pragma unroll
            for (int j = 0; j < 4; ++j) {
                acc[q][i][j][0]=0.f; acc[q][i][j][1]=0.f;
                acc[q][i][j][2]=0.f; acc[q][i][j][3]=0.f;
            }

    // A round a (0..3): wave w stages subtile (rg=4a+(w>>1), kh=w&1), rows rg*16..
    auto stageA = [&](int buf, int a, int k0) {
        const int rg = 4*a + (w >> 1), kh = w & 1;
        gload_lds16(gA + (size_t)(rg*16)*DMODEL + k0 + kh*32,
                    sA + buf*32768 + (rg*2 + kh)*1024);
    };
    // B round b (0..1): wave w stages subtile (rg=4b+(w>>1), kh=w&1)
    auto stageB = [&](int buf, int b, int k0) {
        const int rg = 4*b + (w >> 1), kh = w & 1;
        gload_lds16(gB + (size_t)(rg*16)*DMODEL + k0 + kh*32,
                    sB + buf*16384 + (rg*2 + kh)*1024);
    };

    // ---- prologue: tile 0 -> buf 0 (B first, then A, matching steady order)
    stageB(0, 0, 0); stageB(0, 1, 0);
    stageA(0, 0, 0); stageA(0, 1, 0); stageA(0, 2, 0); stageA(0, 3, 0);
    asm volatile("s_waitcnt vmcnt(0)" ::: "memory");
    __builtin_amdgcn_s_barrier();

    const int NT = DMODEL / 64;   // 16
    for (int t = 0; t < NT; ++t) {
        const int  buf = t & 1;
        const int  k1  = (t + 1) * 64;
        const bool st  = (t + 1 < NT);
        char* const Ab = sA + buf*32768;
        char* const Bb = sB + buf*16384;

        // ================= phase 0: qm = 0 =================
        short8 bf[4][2], af[2][2];
#pragma unroll
        for (int j = 0; j < 4; ++j)
#pragma unroll
            for (int kh = 0; kh < 2; ++kh)
                bf[j][kh] = *(const short8*)(Bb + ((cw*4 + j)*2 + kh)*1024 + laneRd);
#pragma unroll
        for (int i = 0; i < 2; ++i)
#pragma unroll
            for (int kh = 0; kh < 2; ++kh)
                af[i][kh] = *(const short8*)(Ab + ((rw*2 + i)*2 + kh)*1024 + laneRd);

        if (st) { stageB(buf^1, 0, k1); stageB(buf^1, 1, k1); }
        __builtin_amdgcn_s_barrier();

        __builtin_amdgcn_s_setprio(1);
#pragma unroll
        for (int i = 0; i < 2; ++i)
#pragma unroll
            for (int j = 0; j < 4; ++j) {
                acc[0][i][j] = __builtin_amdgcn_mfma_f32_16x16x32_bf16(
                    af[i][0], bf[j][0], acc[0][i][j], 0, 0, 0);
                acc[0][i][j] = __builtin_amdgcn_mfma_f32_16x16x32_bf16(
                    af[i][1], bf[j][1], acc[0][i][j], 0, 0, 0);
            }
        __builtin_amdgcn_s_setprio(0);

        if (st) { asm volatile("s_waitcnt vmcnt(2)" ::: "memory"); }
        else    { asm volatile("s_waitcnt vmcnt(0)" ::: "memory"); }
        __builtin_amdgcn_s_barrier();

        // ================= phase 1: qm = 1 =================
#pragma unroll
        for (int i = 0; i < 2; ++i)
#pragma unroll
            for (int kh = 0; kh < 2; ++kh)
                af[i][kh] = *(const short8*)(Ab + ((8 + rw*2 + i)*2 + kh)*1024 + laneRd);

        if (st) { stageA(buf^1, 0, k1); stageA(buf^1, 1, k1);
                  stageA(buf^1, 2, k1); stageA(buf^1, 3, k1); }
        __builtin_amdgcn_s_barrier();

        __builtin_amdgcn_s_setprio(1);
#pragma unroll
        for (int i = 0; i < 2; ++i)
#pragma unroll
            for (int j = 0; j < 4; ++j) {
                acc[1][i][j] = __builtin_amdgcn_mfma_f32_16x16x32_bf16(
                    af[i][0], bf[j][0], acc[1][i][j], 0, 0, 0);
                acc[1][i][j] = __builtin_amdgcn_mfma_f32_16x16x32_bf16(
                    af[i][1], bf[j][1], acc[1][i][j], 0, 0, 0);
            }
        __builtin_amdgcn_s_setprio(0);

        if (st) { asm volatile("s_waitcnt vmcnt(2)" ::: "memory"); }
        else    { asm volatile("s_waitcnt vmcnt(0)" ::: "memory"); }
        __builtin_amdgcn_s_barrier();
    }

    // ---- epilogue
    float bv[4];
#pragma unroll
    for (int j = 0; j < 4; ++j)
        bv[j] = bias[bn*128 + cw*64 + j*16 + m16];

    if (QKV_MODE) {
        const int seg = bn >> 3;           // 0=Q(scaled), 1=K, 2=V(transposed)
        if (seg < 2) {
            bf16* Cout = (bf16*)(seg ? C1 : C0);
            const float sc = seg ? 1.0f : SCALE_Q;
#pragma unroll
            for (int q = 0; q < 2; ++q)
#pragma unroll
                for (int i = 0; i < 2; ++i)
#pragma unroll
                    for (int r = 0; r < 4; ++r) {
                        const int gm = bm*256 + q*128 + rw*32 + i*16 + quad*4 + r;
#pragma unroll
                        for (int j = 0; j < 4; ++j) {
                            const int cc = ((bn & 7)*128 + cw*64 + j*16 + m16);
                            Cout[(size_t)gm*DMODEL + cc] =
                                __float2bfloat16((acc[q][i][j][r] + bv[j]) * sc);
                        }
                    }
        } else {
            bf16* VT = (bf16*)C2;
#pragma unroll
            for (int q = 0; q < 2; ++q)
#pragma unroll
                for (int i = 0; i < 2; ++i) {
                    const int gm0 = bm*256 + q*128 + rw*32 + i*16 + quad*4;
                    const int bb = gm0 >> 11, t0 = gm0 & 2047;
#pragma unroll
                    for (int j = 0; j < 4; ++j) {
                        const int cv = (bn & 7)*128 + cw*64 + j*16 + m16;
                        const int hh = cv >> 6, dd = cv & 63;
                        union { unsigned long long u8; unsigned short us[4]; } o;
#pragma unroll
                        for (int r = 0; r < 4; ++r)
                            o.us[r] = f2bf_rne(acc[q][i][j][r] + bv[j]);
                        *(unsigned long long*)(VT
                            + ((size_t)((bb*NHEADS + hh)*DHEAD + dd))*SEQ + t0) = o.u8;
                    }
                }
        }
    } else {
        float* Cout = (float*)C0;
#pragma unroll
        for (int q = 0; q < 2; ++q)
#pragma unroll
            for (int i = 0; i < 2; ++i)
#pragma unroll
                for (int r = 0; r < 4; ++r) {
                    const int gm = bm*256 + q*128 + rw*32 + i*16 + quad*4 + r;
#pragma unroll
                    for (int j = 0; j < 4; ++j) {
                        const int cc = bn*128 + cw*64 + j*16 + m16;
                        Cout[(size_t)gm*DMODEL + cc] = acc[q][i][j][r] + bv[j];
                    }
                }
    }
}

// ---------------------------------------------------------------------------
// MFMA flash attention v3 — transposed formulation. S^T = K·Q^T and
// O^T = V^T·P^T via operand-swapped MFMAs. Each lane owns ONE q-column per
// i-group. Q pre-scaled by 0.125*log2(e) -> exp2-based online softmax.
// Block = paired q-tiles {p, 15-p} (uniform 34 iters); dbuf K/V tiles.
// New this round: XCD swizzle (8 p-blocks of one (b,h) share an XCD/L2) +
// defer-max (skip O-rescale while tile max grows < 8 in base-2 units; P
// then bounded by 2^8, safe in bf16/f32 accum).
// ---------------------------------------------------------------------------
__global__ __launch_bounds__(256, 2) void attn_mfma3(
    const bf16* __restrict__ Qg, const bf16* __restrict__ Kg,
    const bf16* __restrict__ VTg, bf16* __restrict__ Og)
{
    __shared__ alignas(16) unsigned short Kt[2][64][72];   // [buf][key][d]
    __shared__ alignas(16) unsigned short Vt[2][64][72];   // [buf][d][key]
    __shared__ alignas(16) unsigned short Ps[4][32][72];   // [wave][q][key] = P^T cols

    // XCD swizzle: x = hlo + 8*(p + 8*t2); h = hlo|((t2&1)<<3); b = t2>>1.
    // All 8 p-blocks of a (b,h) share x%8 -> same XCD -> K/V L2-resident.
    const int x = blockIdx.x;
    const int hlo = x & 7, rest = x >> 3;
    const int p = rest & 7, t2 = rest >> 3;
    const int b = t2 >> 1, h = hlo | ((t2 & 1) << 3);

    const int tid = threadIdx.x;
    const int w = tid >> 6, lane = tid & 63;
    const int m16 = lane & 15, quad = lane >> 4;
    const int sr = tid >> 2, sc0 = (tid & 3) * 8;
    const size_t bh = (size_t)(b*NHEADS + h);

    for (int seg = 0; seg < 2; ++seg) {
        const int qt  = seg ? (15 - p) : p;
        const int nkt = 2*qt + 2;
        const int qrow0 = qt*128 + w*32;

        short8 qf[2][2];
#pragma unroll
        for (int i = 0; i < 2; ++i)
#pragma unroll
            for (int c = 0; c < 2; ++c)
                qf[i][c] = *(const short8*)(Qg + (size_t)(b*SEQ + qrow0 + i*16 + m16)*DMODEL
                                            + h*DHEAD + c*32 + quad*8);

        floatx4 of[2][4];
        float mrow[2], lrow[2];
#pragma unroll
        for (int i = 0; i < 2; ++i) {
            mrow[i] = NEG_BIG; lrow[i] = 0.f;
#pragma unroll
            for (int nt = 0; nt < 4; ++nt) { of[i][nt][0]=0.f; of[i][nt][1]=0.f; of[i][nt][2]=0.f; of[i][nt][3]=0.f; }
        }

        // ---- stage tile 0 into buf 0
        {
            const bf16* kp = Kg  + (size_t)(b*SEQ + sr)*DMODEL + h*DHEAD + sc0;
            const bf16* vp = VTg + (bh*DHEAD + sr)*SEQ + sc0;
            const uint4 a0 = *(const uint4*)kp, a1 = *(const uint4*)(kp + 32);
            const uint4 b0 = *(const uint4*)vp, b1 = *(const uint4*)(vp + 32);
            __syncthreads();
            *(uint4*)&Kt[0][sr][sc0]      = a0;
            *(uint4*)&Kt[0][sr][sc0 + 32] = a1;
            *(uint4*)&Vt[0][sr][sc0]      = b0;
            *(uint4*)&Vt[0][sr][sc0 + 32] = b1;
            __syncthreads();
        }

        for (int kt = 0; kt < nkt; ++kt) {
            const int buf = kt & 1;
            const int k064 = kt * 64;
            const bool pre = (kt + 1 < nkt);
            uint4 kr0, kr1, vr0, vr1;
            if (pre) {
                const bf16* kp = Kg  + (size_t)(b*SEQ + k064 + 64 + sr)*DMODEL + h*DHEAD + sc0;
                const bf16* vp = VTg + (bh*DHEAD + sr)*SEQ + k064 + 64 + sc0;
                kr0 = *(const uint4*)kp; kr1 = *(const uint4*)(kp + 32);
                vr0 = *(const uint4*)vp; vr1 = *(const uint4*)(vp + 32);
            }

            // ---- S^T = K Q^T (16 MFMA): rows=key(quad*4+r, t4), cols=q(m16)
            floatx4 sf[2][4];
#pragma unroll
            for (int t4 = 0; t4 < 4; ++t4) {
                const short8 kf0 = *(const short8*)&Kt[buf][t4*16 + m16][quad*8];
                const short8 kf1 = *(const short8*)&Kt[buf][t4*16 + m16][32 + quad*8];
#pragma unroll
                for (int i = 0; i < 2; ++i) {
                    floatx4 a; a[0]=0.f; a[1]=0.f; a[2]=0.f; a[3]=0.f;
                    a = __builtin_amdgcn_mfma_f32_16x16x32_bf16(kf0, qf[i][0], a, 0, 0, 0);
                    a = __builtin_amdgcn_mfma_f32_16x16x32_bf16(kf1, qf[i][1], a, 0, 0, 0);
                    sf[i][t4] = a;
                }
            }

            // ---- online softmax (per lane = per q-column), defer-max
            const bool need_mask = (k064 + 63 > qrow0);
#pragma unroll
            for (int i = 0; i < 2; ++i) {
                if (need_mask) {
                    const int qg = qrow0 + i*16 + m16;
#pragma unroll
                    for (int t4 = 0; t4 < 4; ++t4)
#pragma unroll
                        for (int r = 0; r < 4; ++r)
                            if (k064 + t4*16 + quad*4 + r > qg) sf[i][t4][r] = NEG_BIG;
                }
                float mx = sf[i][0][0];
#pragma unroll
                for (int t4 = 0; t4 < 4; ++t4)
#pragma unroll
                    for (int r = 0; r < 4; ++r) mx = fmaxf(mx, sf[i][t4][r]);
                mx = fmaxf(mx, __shfl_xor(mx, 16));
                mx = fmaxf(mx, __shfl_xor(mx, 32));

                // defer-max: only rescale when the tile max meaningfully grows.
                // S is in base-2 log units; THR=8 bounds P by 2^8=256 (safe).
                if (__any(mx > mrow[i] + 8.f)) {
                    const float mnew  = fmaxf(mrow[i], mx);
                    const float alpha = exp2f(mrow[i] - mnew);
                    mrow[i] = mnew;
                    lrow[i] *= alpha;
#pragma unroll
                    for (int nt = 0; nt < 4; ++nt)
#pragma unroll
                        for (int r = 0; r < 4; ++r) of[i][nt][r] *= alpha;
                }

                float rs = 0.f;
#pragma unroll
                for (int t4 = 0; t4 < 4; ++t4) {
#pragma unroll
                    for (int r = 0; r < 4; ++r) {
                        const float pv = exp2f(sf[i][t4][r] - mrow[i]);
                        sf[i][t4][r] = pv;
                        rs += pv;
                    }
                }
                rs += __shfl_xor(rs, 16);
                rs += __shfl_xor(rs, 32);
                lrow[i] += rs;

                // P^T -> LDS: 4 consecutive keys per b64 store
#pragma unroll
                for (int t4 = 0; t4 < 4; ++t4) {
                    union { unsigned long long u8; unsigned short us[4]; } o;
#pragma unroll
                    for (int r = 0; r < 4; ++r) o.us[r] = f2bf_rne(sf[i][t4][r]);
                    *(unsigned long long*)&Ps[w][i*16 + m16][t4*16 + quad*4] = o.u8;
                }
            }

            // ---- O^T += V^T P^T (16 MFMA); Ps wave-local
            short8 pf[2][2];
#pragma unroll
            for (int i = 0; i < 2; ++i)
#pragma unroll
                for (int c = 0; c < 2; ++c)
                    pf[i][c] = *(const short8*)&Ps[w][i*16 + m16][c*32 + quad*8];
#pragma unroll
            for (int nt = 0; nt < 4; ++nt) {
                const short8 vf0 = *(const short8*)&Vt[buf][nt*16 + m16][quad*8];
                const short8 vf1 = *(const short8*)&Vt[buf][nt*16 + m16][32 + quad*8];
#pragma unroll
                for (int i = 0; i < 2; ++i) {
                    of[i][nt] = __builtin_amdgcn_mfma_f32_16x16x32_bf16(vf0, pf[i][0], of[i][nt], 0, 0, 0);
                    of[i][nt] = __builtin_amdgcn_mfma_f32_16x16x32_bf16(vf1, pf[i][1], of[i][nt], 0, 0, 0);
                }
            }

            if (pre) {
                *(uint4*)&Kt[buf^1][sr][sc0]      = kr0;
                *(uint4*)&Kt[buf^1][sr][sc0 + 32] = kr1;
                *(uint4*)&Vt[buf^1][sr][sc0]      = vr0;
                *(uint4*)&Vt[buf^1][sr][sc0 + 32] = vr1;
            }
            __syncthreads();
        }

        // ---- normalize + store O: lane owns row q, dims nt*16+quad*4+{0..3}
#pragma unroll
        for (int i = 0; i < 2; ++i) {
            const float rl = 1.f / fmaxf(lrow[i], 1e-20f);
            const size_t rowbase = (size_t)(b*SEQ + qrow0 + i*16 + m16)*DMODEL + h*DHEAD;
#pragma unroll
            for (int nt = 0; nt < 4; ++nt) {
                union { unsigned long long u8; unsigned short us[4]; } o;
#pragma unroll
                for (int r = 0; r < 4; ++r) o.us[r] = f2bf_rne(of[i][nt][r] * rl);
                *(unsigned long long*)(Og + rowbase + nt*16 + quad*4) = o.u8;
            }
        }
    }
}

__global__ void diag_fill(float* out, int n, float val) {
    int i = blockIdx.x*blockDim.x + threadIdx.x;
    if (i < n) out[i] = val;
}

// ---------------------------------------------------------------------------
extern "C" void kernel_launch(void* const* d_in, const int* in_sizes, int n_in,
                              void* d_out, int out_size, void* d_ws, size_t ws_size,
                              hipStream_t stream) {
    const float* x     = (const float*)d_in[0];
    const float* W_qkv = (const float*)d_in[1];
    const float* b_qkv = (const float*)d_in[2];
    const float* W_out = (const float*)d_in[3];
    const float* b_out = (const float*)d_in[4];

    if (ws_size < WS_NEED) {
        const float val = 100.f + (float)(ws_size >> 20);
        diag_fill<<<(out_size + 255)/256, 256, 0, stream>>>((float*)d_out, out_size, val);
        return;
    }

    bf16* Qb  = (bf16*)d_out;                                // d_out lo: Q (pre-scaled)
    bf16* VTb = (bf16*)d_out + (size_t)MROWS*DMODEL;         // d_out hi: VT
    bf16* Kb  = (bf16*)d_ws;                                 // ws lo: K
    bf16* Ob  = (bf16*)d_ws + (size_t)MROWS*DMODEL;          // ws hi: O

    // 0) casts
    cast_x<<<MROWS*DMODEL/2048, 256, 0, stream>>>(x);
    {
        dim3 gq(QKV_N/64, DMODEL/64);
        transcast_w<<<gq, 256, 0, stream>>>(W_qkv, QKV_N, 0);
        dim3 go(DMODEL/64, DMODEL/64);
        transcast_w<<<go, 256, 0, stream>>>(W_out, DMODEL, 1);
    }
    // 1) fused QKV projection; Q pre-scaled; V pre-transposed (256x128 tiles,
    //    768 blocks = 3.0 clean rounds)
    {
        gemm256x128<1><<<768, 512, 0, stream>>>(nullptr, b_qkv, Qb, Kb, VTb);
    }
    // 2) flash attention v3 (transposed MFMA formulation, XCD-swizzled)
    {
        attn_mfma3<<<512, 256, 0, stream>>>(Qb, Kb, VTb, Ob);
    }
    // 3) output projection: O bf16 -> fp32 d_out (256 blocks = 1.0 round)
    {
        gemm256x128<0><<<256, 512, 0, stream>>>(Ob, b_out, d_out, nullptr, nullptr);
    }
}